// Round 15
// baseline (884.184 us; speedup 1.0000x reference)
//
#include <hip/hip_runtime.h>
#include <math.h>

#define TWO32F 4294967296.0f

// Raw v_ldexp_f32 (IEEE scalbn) — identical bits to ldexpf, no OCML clamp code.
__device__ __forceinline__ float ldx(float p, int q) {
#if __has_builtin(__builtin_amdgcn_ldexpf)
    return __builtin_amdgcn_ldexpf(p, q);
#else
    return ldexpf(p, q);
#endif
}

// ---- Bit-exact replica of numpy's SIMD float32 exp (loops_exponent_log) ----
__device__ __forceinline__ float np_expf(float x) {
    const float LOG2E = 1.44269504088896341f;   // 0x3FB8AA3B
    const float MAGIC = 12582912.0f;            // 1.5 * 2^23 (RNE int round)
    const float CW1 = 0.693359375f;             // ln2 hi
    const float CW2 = -2.12194440e-4f;          // ln2 lo
    float q = __builtin_fmaf(x, LOG2E, MAGIC);
    q = q - MAGIC;
    float r = __builtin_fmaf(-q, CW1, x);
    r = __builtin_fmaf(-q, CW2, r);
    float p = 1.9875691500e-4f;
    p = __builtin_fmaf(p, r, 1.3981999507e-3f);
    p = __builtin_fmaf(p, r, 8.3334519073e-3f);
    p = __builtin_fmaf(p, r, 4.1665795894e-2f);
    p = __builtin_fmaf(p, r, 1.6666665459e-1f);
    p = __builtin_fmaf(p, r, 5.0000001201e-1f);
    float r2 = r * r;
    p = __builtin_fmaf(p, r2, r);
    p = p + 1.0f;
    return ldx(p, (int)q);
}

__device__ __forceinline__ float sigmoid_np(float w) {
    #pragma clang fp contract(off)
    float e = np_expf(-w);
    float d = 1.0f + e;
    return 1.0f / d;             // IEEE CR divide
}

__device__ __forceinline__ float soft_xor(float x, float y) {
    #pragma clang fp contract(off)
    float wx = 10.0f * (x - 0.5f);
    float xs = sigmoid_np(wx);
    float wy = 10.0f * (y - 0.5f);
    float ys = sigmoid_np(wy);
    float omys = 1.0f - ys;
    float t1   = xs * omys;
    float omxs = 1.0f - xs;
    float t2   = omxs * ys;
    float s    = t1 + t2;
    float t12  = t1 * t2;
    float r    = s - t12;
    r = fmaxf(r, 0.0f);
    r = fminf(r, 1.0f);
    return r;
}

__device__ __forceinline__ float soft_add(float x, float y) {
    #pragma clang fp contract(off)
    float s  = x + y;
    float d  = s - 1.0f;
    float w  = 10.0f * d;
    float sg = sigmoid_np(w);
    return s - sg;
}

template <int N>
__device__ __forceinline__ float rotl(float x) {
    #pragma clang fp contract(off)
    const float PN = (float)(1u << N);
    const float PN_INV32 = PN / TWO32F;
    float xs = x * TWO32F;
    float a  = xs * PN;
    float q1 = floorf(a * (1.0f / TWO32F));
    float sl = a - q1 * TWO32F;
    float sr = xs * PN_INV32;
    float s2 = sl + sr;
    float q2 = floorf(s2 * (1.0f / TWO32F));
    float r  = s2 - q2 * TWO32F;
    return r * (1.0f / TWO32F);
}

// One quarter-round stage pair: two independent elements (u, v) interleaved
// stage-by-stage for ILP. Per-element FP sequence identical to scalar version.
template <int IA, int IB, int IC, int ID>
__device__ __forceinline__ void qr2(float* u, float* v) {
    {
        float au = soft_add(u[IA], u[ID]); float av = soft_add(v[IA], v[ID]);
        float ru = rotl<7>(au);            float rv = rotl<7>(av);
        u[IB] = soft_xor(u[IB], ru);       v[IB] = soft_xor(v[IB], rv);
    }
    {
        float au = soft_add(u[IB], u[IA]); float av = soft_add(v[IB], v[IA]);
        float ru = rotl<9>(au);            float rv = rotl<9>(av);
        u[IC] = soft_xor(u[IC], ru);       v[IC] = soft_xor(v[IC], rv);
    }
    {
        float au = soft_add(u[IC], u[IB]); float av = soft_add(v[IC], v[IB]);
        float ru = rotl<13>(au);           float rv = rotl<13>(av);
        u[ID] = soft_xor(u[ID], ru);       v[ID] = soft_xor(v[ID], rv);
    }
    {
        float au = soft_add(u[ID], u[IC]); float av = soft_add(v[ID], v[IC]);
        float ru = rotl<18>(au);           float rv = rotl<18>(av);
        u[IA] = soft_xor(u[IA], ru);       v[IA] = soft_xor(v[IA], rv);
    }
}

__global__ __launch_bounds__(256) void salsa20_soft_kernel(
    const float* __restrict__ pt, const float* __restrict__ key,
    const float* __restrict__ nonce, float* __restrict__ out, int Bpairs) {
    #pragma clang fp contract(off)
    int i = blockIdx.x * 256 + threadIdx.x;
    if (i >= Bpairs) return;
    size_t e0 = (size_t)i * 2;
    size_t e1 = e0 + 1;

    const float C0 = 1634760805.0f / 4294967296.0f;
    const float C1 = 857760878.0f  / 4294967296.0f;
    const float C2 = 2036477234.0f / 4294967296.0f;
    const float C3 = 1797285236.0f / 4294967296.0f;

    const float4* k4 = reinterpret_cast<const float4*>(key);
    float4 ka0 = k4[e0 * 2], kb0 = k4[e0 * 2 + 1];
    float4 ka1 = k4[e1 * 2], kb1 = k4[e1 * 2 + 1];
    float4 nn = reinterpret_cast<const float4*>(nonce)[i];  // e0:{x,y} e1:{z,w}

    float wA[16], wB[16];
    wA[0]=C0;    wA[1]=ka0.x; wA[2]=ka0.y; wA[3]=ka0.z;
    wA[4]=ka0.w; wA[5]=C1;    wA[6]=nn.x;  wA[7]=nn.y;
    wA[8]=0.0f;  wA[9]=0.0f;  wA[10]=C2;   wA[11]=kb0.x;
    wA[12]=kb0.y;wA[13]=kb0.z;wA[14]=kb0.w;wA[15]=C3;
    wB[0]=C0;    wB[1]=ka1.x; wB[2]=ka1.y; wB[3]=ka1.z;
    wB[4]=ka1.w; wB[5]=C1;    wB[6]=nn.z;  wB[7]=nn.w;
    wB[8]=0.0f;  wB[9]=0.0f;  wB[10]=C2;   wB[11]=kb1.x;
    wB[12]=kb1.y;wB[13]=kb1.z;wB[14]=kb1.w;wB[15]=C3;

    float iA[16], iB[16];
    #pragma unroll
    for (int j = 0; j < 16; ++j) { iA[j] = wA[j]; iB[j] = wB[j]; }

    #pragma unroll 1
    for (int r = 0; r < 10; ++r) {
        qr2<0, 4, 8, 12>(wA, wB);
        qr2<5, 9, 13, 1>(wA, wB);
        qr2<10, 14, 2, 6>(wA, wB);
        qr2<15, 3, 7, 11>(wA, wB);
        qr2<0, 1, 2, 3>(wA, wB);
        qr2<5, 6, 7, 4>(wA, wB);
        qr2<10, 11, 8, 9>(wA, wB);
        qr2<15, 12, 13, 14>(wA, wB);
    }

    const float4* p4 = reinterpret_cast<const float4*>(pt);
    float4* o4 = reinterpret_cast<float4*>(out);
    #pragma unroll
    for (int q = 0; q < 4; ++q) {
        float4 pA = p4[e0 * 4 + q];
        float4 pB = p4[e1 * 4 + q];
        float4 oA, oB;
        oA.x = soft_xor(pA.x, soft_add(wA[4*q+0], iA[4*q+0]));
        oB.x = soft_xor(pB.x, soft_add(wB[4*q+0], iB[4*q+0]));
        oA.y = soft_xor(pA.y, soft_add(wA[4*q+1], iA[4*q+1]));
        oB.y = soft_xor(pB.y, soft_add(wB[4*q+1], iB[4*q+1]));
        oA.z = soft_xor(pA.z, soft_add(wA[4*q+2], iA[4*q+2]));
        oB.z = soft_xor(pB.z, soft_add(wB[4*q+2], iB[4*q+2]));
        oA.w = soft_xor(pA.w, soft_add(wA[4*q+3], iA[4*q+3]));
        oB.w = soft_xor(pB.w, soft_add(wB[4*q+3], iB[4*q+3]));
        o4[e0 * 4 + q] = oA;
        o4[e1 * 4 + q] = oB;
    }
}

extern "C" void kernel_launch(void* const* d_in, const int* in_sizes, int n_in,
                              void* d_out, int out_size, void* d_ws, size_t ws_size,
                              hipStream_t stream) {
    const float* pt    = (const float*)d_in[0];
    const float* key   = (const float*)d_in[1];
    const float* nonce = (const float*)d_in[2];
    float* out = (float*)d_out;
    int B = in_sizes[0] / 16;
    int Bpairs = B / 2;               // B = 1048576, even
    int grid = (Bpairs + 255) / 256;
    salsa20_soft_kernel<<<grid, 256, 0, stream>>>(pt, key, nonce, out, Bpairs);
}

// Round 16
// 825.366 us; speedup vs baseline: 1.0713x; 1.0713x over previous
//
#include <hip/hip_runtime.h>
#include <math.h>

#define TWO32F 4294967296.0f

typedef float v2f __attribute__((ext_vector_type(2)));

__device__ __forceinline__ v2f splat(float c) { v2f r; r.x = c; r.y = c; return r; }
__device__ __forceinline__ v2f vfma(v2f a, v2f b, v2f c) { return __builtin_elementwise_fma(a, b, c); }
__device__ __forceinline__ v2f vfloor(v2f a) { return __builtin_elementwise_floor(a); }
__device__ __forceinline__ v2f vmaxv(v2f a, v2f b) { return __builtin_elementwise_max(a, b); }
__device__ __forceinline__ v2f vminv(v2f a, v2f b) { return __builtin_elementwise_min(a, b); }

// Raw v_ldexp_f32 (IEEE scalbn) — identical bits to ldexpf, no OCML clamp code.
__device__ __forceinline__ float ldx(float p, int q) {
#if __has_builtin(__builtin_amdgcn_ldexpf)
    return __builtin_amdgcn_ldexpf(p, q);
#else
    return ldexpf(p, q);
#endif
}

// ---- numpy SIMD f32 exp replica, two independent lanes packed as v2f ----
// Per-component op sequence identical to the verified scalar np_expf.
__device__ __forceinline__ v2f np_expf_v2(v2f x) {
    #pragma clang fp contract(off)
    const float LOG2E = 1.44269504088896341f;
    const float MAGIC = 12582912.0f;            // 1.5 * 2^23
    const float CW1 = 0.693359375f;
    const float CW2 = -2.12194440e-4f;
    v2f q = vfma(x, splat(LOG2E), splat(MAGIC));
    q = q - MAGIC;
    v2f r = vfma(-q, splat(CW1), x);
    r = vfma(-q, splat(CW2), r);
    v2f p = splat(1.9875691500e-4f);
    p = vfma(p, r, splat(1.3981999507e-3f));
    p = vfma(p, r, splat(8.3334519073e-3f));
    p = vfma(p, r, splat(4.1665795894e-2f));
    p = vfma(p, r, splat(1.6666665459e-1f));
    p = vfma(p, r, splat(5.0000001201e-1f));
    v2f r2 = r * r;
    p = vfma(p, r2, r);
    p = p + 1.0f;
    v2f res;
    res.x = ldx(p.x, (int)q.x);
    res.y = ldx(p.y, (int)q.y);
    return res;
}

__device__ __forceinline__ v2f sigmoid_v2(v2f w) {
    #pragma clang fp contract(off)
    v2f e = np_expf_v2(-w);
    v2f d = e + 1.0f;            // 1 rounding per component
    v2f one = splat(1.0f);
    return one / d;              // scalarizes to 2 IEEE CR divides
}

__device__ __forceinline__ v2f soft_xor_v2(v2f x, v2f y) {
    #pragma clang fp contract(off)
    v2f wx = (x - 0.5f) * 10.0f;
    v2f xs = sigmoid_v2(wx);
    v2f wy = (y - 0.5f) * 10.0f;
    v2f ys = sigmoid_v2(wy);
    v2f omys = 1.0f - ys;
    v2f t1   = xs * omys;
    v2f omxs = 1.0f - xs;
    v2f t2   = omxs * ys;
    v2f s    = t1 + t2;
    v2f t12  = t1 * t2;
    v2f r    = s - t12;
    r = vmaxv(r, splat(0.0f));
    r = vminv(r, splat(1.0f));
    return r;
}

__device__ __forceinline__ v2f soft_add_v2(v2f x, v2f y) {
    #pragma clang fp contract(off)
    v2f s  = x + y;
    v2f d  = s - 1.0f;
    v2f w  = d * 10.0f;
    v2f sg = sigmoid_v2(w);
    return s - sg;
}

// NOTE: mirror the scalar-verified op order exactly:
// wx = 10.0f * (x - 0.5f) in scalar was mul(10, sub) — here (x-0.5f)*10.0f is
// the same two ops (sub then mul), commuted multiplicands (IEEE mul commutes).

template <int N>
__device__ __forceinline__ v2f rotl_v2(v2f x) {
    #pragma clang fp contract(off)
    const float PN = (float)(1u << N);
    const float PN_INV32 = PN / TWO32F;
    v2f xs = x * TWO32F;
    v2f a  = xs * PN;
    v2f q1 = vfloor(a * (1.0f / TWO32F));
    v2f sl = a - q1 * TWO32F;
    v2f sr = xs * PN_INV32;
    v2f s2 = sl + sr;
    v2f q2 = vfloor(s2 * (1.0f / TWO32F));
    v2f r  = s2 - q2 * TWO32F;
    return r * (1.0f / TWO32F);
}

template <int IA, int IB, int IC, int ID>
__device__ __forceinline__ void qrv(v2f* u) {
    u[IB] = soft_xor_v2(u[IB], rotl_v2<7>(soft_add_v2(u[IA], u[ID])));
    u[IC] = soft_xor_v2(u[IC], rotl_v2<9>(soft_add_v2(u[IB], u[IA])));
    u[ID] = soft_xor_v2(u[ID], rotl_v2<13>(soft_add_v2(u[IC], u[IB])));
    u[IA] = soft_xor_v2(u[IA], rotl_v2<18>(soft_add_v2(u[ID], u[IC])));
}

__global__ __launch_bounds__(256) void salsa20_soft_kernel(
    const float* __restrict__ pt, const float* __restrict__ key,
    const float* __restrict__ nonce, float* __restrict__ out, int Bpairs) {
    #pragma clang fp contract(off)
    int i = blockIdx.x * 256 + threadIdx.x;
    if (i >= Bpairs) return;
    size_t e0 = (size_t)i * 2;
    size_t e1 = e0 + 1;

    const float C0 = 1634760805.0f / 4294967296.0f;
    const float C1 = 857760878.0f  / 4294967296.0f;
    const float C2 = 2036477234.0f / 4294967296.0f;
    const float C3 = 1797285236.0f / 4294967296.0f;

    const float4* k4 = reinterpret_cast<const float4*>(key);
    float4 ka0 = k4[e0 * 2], kb0 = k4[e0 * 2 + 1];
    float4 ka1 = k4[e1 * 2], kb1 = k4[e1 * 2 + 1];
    float4 nn = reinterpret_cast<const float4*>(nonce)[i];  // e0:{x,y} e1:{z,w}

    v2f w[16];
    w[0]  = splat(C0);
    w[1]  = v2f{ka0.x, ka1.x};
    w[2]  = v2f{ka0.y, ka1.y};
    w[3]  = v2f{ka0.z, ka1.z};
    w[4]  = v2f{ka0.w, ka1.w};
    w[5]  = splat(C1);
    w[6]  = v2f{nn.x, nn.z};
    w[7]  = v2f{nn.y, nn.w};
    w[8]  = splat(0.0f);
    w[9]  = splat(0.0f);
    w[10] = splat(C2);
    w[11] = v2f{kb0.x, kb1.x};
    w[12] = v2f{kb0.y, kb1.y};
    w[13] = v2f{kb0.z, kb1.z};
    w[14] = v2f{kb0.w, kb1.w};
    w[15] = splat(C3);

    v2f init[16];
    #pragma unroll
    for (int j = 0; j < 16; ++j) init[j] = w[j];

    #pragma unroll 1
    for (int r = 0; r < 10; ++r) {
        qrv<0, 4, 8, 12>(w);
        qrv<5, 9, 13, 1>(w);
        qrv<10, 14, 2, 6>(w);
        qrv<15, 3, 7, 11>(w);
        qrv<0, 1, 2, 3>(w);
        qrv<5, 6, 7, 4>(w);
        qrv<10, 11, 8, 9>(w);
        qrv<15, 12, 13, 14>(w);
    }

    const float4* p4 = reinterpret_cast<const float4*>(pt);
    float4* o4 = reinterpret_cast<float4*>(out);
    #pragma unroll
    for (int q = 0; q < 4; ++q) {
        float4 pA = p4[e0 * 4 + q];
        float4 pB = p4[e1 * 4 + q];
        v2f o0 = soft_xor_v2(v2f{pA.x, pB.x}, soft_add_v2(w[4*q+0], init[4*q+0]));
        v2f o1 = soft_xor_v2(v2f{pA.y, pB.y}, soft_add_v2(w[4*q+1], init[4*q+1]));
        v2f o2 = soft_xor_v2(v2f{pA.z, pB.z}, soft_add_v2(w[4*q+2], init[4*q+2]));
        v2f o3 = soft_xor_v2(v2f{pA.w, pB.w}, soft_add_v2(w[4*q+3], init[4*q+3]));
        float4 oA, oB;
        oA.x = o0.x; oB.x = o0.y;
        oA.y = o1.x; oB.y = o1.y;
        oA.z = o2.x; oB.z = o2.y;
        oA.w = o3.x; oB.w = o3.y;
        o4[e0 * 4 + q] = oA;
        o4[e1 * 4 + q] = oB;
    }
}

extern "C" void kernel_launch(void* const* d_in, const int* in_sizes, int n_in,
                              void* d_out, int out_size, void* d_ws, size_t ws_size,
                              hipStream_t stream) {
    const float* pt    = (const float*)d_in[0];
    const float* key   = (const float*)d_in[1];
    const float* nonce = (const float*)d_in[2];
    float* out = (float*)d_out;
    int B = in_sizes[0] / 16;
    int Bpairs = B / 2;               // B = 1048576, even
    int grid = (Bpairs + 255) / 256;
    salsa20_soft_kernel<<<grid, 256, 0, stream>>>(pt, key, nonce, out, Bpairs);
}